// Round 1
// baseline (340.029 us; speedup 1.0000x reference)
//
#include <hip/hip_runtime.h>

// IDWT 2D Haar synthesis, fully collapsed:
// each input pixel (i,j) of {LL,LH,HL,HH} -> 2x2 output block at (2i,2j).
// Shapes: in (32,128,56,56) f32 each; out (32,128,112,112) f32.

#define H_IN   56
#define W_IN   56
#define W2     (W_IN / 2)            // 28 float2 per input row
#define H_OUT  112
#define W_OUT  112
#define PLANE_OUT (H_OUT * W_OUT)    // 12544

__global__ __launch_bounds__(256) void idwt_haar_kernel(
    const float* __restrict__ LL, const float* __restrict__ LH,
    const float* __restrict__ HL, const float* __restrict__ HH,
    float* __restrict__ out, int total2)
{
    const int idx = blockIdx.x * 256 + threadIdx.x;   // one float2 of input
    if (idx >= total2) return;

    // idx = ((bc*H_IN) + i)*W2 + w2  ; flat input float offset = 2*idx
    const int w2   = idx % W2;
    const int rest = idx / W2;        // bc*H_IN + i
    const int i    = rest % H_IN;
    const int bc   = rest / H_IN;

    const float2 a = *reinterpret_cast<const float2*>(LL + 2 * idx);
    const float2 b = *reinterpret_cast<const float2*>(LH + 2 * idx);
    const float2 c = *reinterpret_cast<const float2*>(HL + 2 * idx);
    const float2 d = *reinterpret_cast<const float2*>(HH + 2 * idx);

    float4 r0, r1;
    r0.x = 0.5f * (a.x + b.x + c.x + d.x);   // (2i,   2j)
    r0.y = 0.5f * (a.x - b.x + c.x - d.x);   // (2i,   2j+1)
    r0.z = 0.5f * (a.y + b.y + c.y + d.y);   // (2i,   2j+2)
    r0.w = 0.5f * (a.y - b.y + c.y - d.y);   // (2i,   2j+3)
    r1.x = 0.5f * (a.x + b.x - c.x - d.x);   // (2i+1, 2j)
    r1.y = 0.5f * (a.x - b.x - c.x + d.x);   // (2i+1, 2j+1)
    r1.z = 0.5f * (a.y + b.y - c.y - d.y);   // (2i+1, 2j+2)
    r1.w = 0.5f * (a.y - b.y - c.y + d.y);   // (2i+1, 2j+3)

    const int out_base = bc * PLANE_OUT + (2 * i) * W_OUT + 4 * w2;
    *reinterpret_cast<float4*>(out + out_base)         = r0;   // row 2i
    *reinterpret_cast<float4*>(out + out_base + W_OUT) = r1;   // row 2i+1
}

extern "C" void kernel_launch(void* const* d_in, const int* in_sizes, int n_in,
                              void* d_out, int out_size, void* d_ws, size_t ws_size,
                              hipStream_t stream) {
    const float* LL = (const float*)d_in[0];
    const float* LH = (const float*)d_in[1];
    const float* HL = (const float*)d_in[2];
    const float* HH = (const float*)d_in[3];
    float* out = (float*)d_out;

    const int total2 = in_sizes[0] / 2;               // 6,422,528 float2 elems
    const int blocks = (total2 + 255) / 256;          // 25088 (exact)

    idwt_haar_kernel<<<blocks, 256, 0, stream>>>(LL, LH, HL, HH, out, total2);
}